// Round 4
// baseline (244.056 us; speedup 1.0000x reference)
//
#include <hip/hip_runtime.h>

typedef __bf16 bf16x8 __attribute__((ext_vector_type(8)));
typedef float f32x4 __attribute__((ext_vector_type(4)));
typedef unsigned short u16x4 __attribute__((ext_vector_type(4)));
typedef unsigned short u16x8 __attribute__((ext_vector_type(8)));
typedef unsigned int u32x4 __attribute__((ext_vector_type(4)));

__device__ __forceinline__ float bf2f(unsigned short h) {
    union { unsigned int u; float f; } v;
    v.u = ((unsigned int)h) << 16;
    return v.f;
}
__device__ __forceinline__ unsigned short f2bf(float f) {
    return __builtin_bit_cast(unsigned short, (__bf16)f);  // native v_cvt, RNE
}
// async global->LDS, 16B per lane; LDS dest = wave-uniform base + lane*16
__device__ __forceinline__ void glds16(const unsigned short* g, unsigned short* l) {
    __builtin_amdgcn_global_load_lds((__attribute__((address_space(1))) void*)g,
                                     (__attribute__((address_space(3))) void*)l,
                                     16, 0, 0);
}

#define MFMA16(a, b, c) __builtin_amdgcn_mfma_f32_16x16x32_bf16((a), (b), (c), 0, 0, 0)

// ---------------------------------------------------------------------------
// prep1: X f32->bf16 cvt (blocks 0..4095) + merged Wq|Wk|Wv f32->bf16
// transpose into wqkvT[3072][2048] (blocks 4096..10239)
// ---------------------------------------------------------------------------
__global__ __launch_bounds__(256) void prep1(const float* __restrict__ X,
                                             const float* __restrict__ Wq,
                                             const float* __restrict__ Wk,
                                             const float* __restrict__ Wv,
                                             unsigned short* __restrict__ Xbf,
                                             unsigned short* __restrict__ wqkvT) {
    const int b = blockIdx.x;
    const int tid = threadIdx.x;
    if (b < 4096) {
        const int i = (b * 256 + tid) * 4;
        const float4 v = *(const float4*)(X + i);
        u16x4 o;
        o[0] = f2bf(v.x); o[1] = f2bf(v.y); o[2] = f2bf(v.z); o[3] = f2bf(v.w);
        *(u16x4*)(Xbf + i) = o;
        return;
    }
    __shared__ __align__(16) unsigned short tile[32][33];
    const int tx = tid & 31, ty = tid >> 5;
    const int b2 = b - 4096;
    const int kb = (b2 & 63) * 32;   // k-dim base (rows of W)
    const int nb = (b2 >> 6) * 32;   // fused out-col base 0..3071
    const float* src; int scol, sld;
    if (nb < 2048)      { src = Wq; scol = nb;        sld = 2048; }
    else if (nb < 2560) { src = Wk; scol = nb - 2048; sld = 512;  }
    else                { src = Wv; scol = nb - 2560; sld = 512;  }
#pragma unroll
    for (int i = 0; i < 32; i += 8)
        tile[ty + i][tx] = f2bf(src[(size_t)(kb + ty + i) * sld + (scol + tx)]);
    __syncthreads();
#pragma unroll
    for (int i = 0; i < 32; i += 8)
        wqkvT[(size_t)(nb + ty + i) * 2048 + (kb + tx)] = tile[tx][ty + i];
}

// ---------------------------------------------------------------------------
// prep2 (post-QKV GEMM): Wo f32->bf16 transpose -> woT (blocks 0..4095)
// + V bf16 transpose qkv[:,2560:3072] -> vt[512][2048] (blocks 4096..5119)
// ---------------------------------------------------------------------------
__global__ __launch_bounds__(256) void prep2(const float* __restrict__ Wo,
                                             const unsigned short* __restrict__ qkv,
                                             unsigned short* __restrict__ woT,
                                             unsigned short* __restrict__ vt) {
    const int b = blockIdx.x;
    const int tid = threadIdx.x;
    const int tx = tid & 31, ty = tid >> 5;
    __shared__ __align__(16) unsigned short tile[32][33];
    if (b < 4096) {
        const int kb = (b & 63) * 32;
        const int nb = (b >> 6) * 32;
#pragma unroll
        for (int i = 0; i < 32; i += 8)
            tile[ty + i][tx] = f2bf(Wo[(size_t)(kb + ty + i) * 2048 + (nb + tx)]);
        __syncthreads();
#pragma unroll
        for (int i = 0; i < 32; i += 8)
            woT[(size_t)(nb + ty + i) * 2048 + (kb + tx)] = tile[tx][ty + i];
    } else {
        const int b2 = b - 4096;
        const int bx = (b2 & 15) * 32;   // d-col base in V (0..511)
        const int by = (b2 >> 4) * 32;   // s-row base (0..2047)
#pragma unroll
        for (int i = 0; i < 32; i += 8)
            tile[ty + i][tx] = qkv[(size_t)(by + ty + i) * 3072 + 2560 + bx + tx];
        __syncthreads();
#pragma unroll
        for (int i = 0; i < 32; i += 8)
            vt[(size_t)(bx + ty + i) * 2048 + (by + tx)] = tile[tx][ty + i];
    }
}

// ---------------------------------------------------------------------------
// gemm128_qkv: QKV = Xbf @ wqkvT^T, m97-exact 128x128 tile BK=64, 4 waves
// 2x2 (64x64/wave), glds16 staging, RoPE fused, bf16 out ldc=3072.
// ---------------------------------------------------------------------------
__global__ __launch_bounds__(256) void gemm128_qkv(const unsigned short* __restrict__ A,
                                                   const unsigned short* __restrict__ BT,
                                                   unsigned short* __restrict__ C) {
    __shared__ __align__(16) unsigned short As[128 * 64];
    __shared__ __align__(16) unsigned short Bs[128 * 64];

    const int tid = threadIdx.x;
    const int lane = tid & 63;
    const int wave = tid >> 6;
    const int quad = lane >> 4;
    const int l15 = lane & 15;
    const int bm = blockIdx.x * 128;
    const int bn = blockIdx.y * 128;
    const int wm = (wave & 1) * 64;
    const int wn = (wave >> 1) * 64;

    const int srow = wave * 8 + (lane >> 3);      // 0..31 (+32 per call)
    const int sw8 = (lane & 7) ^ (srow & 7);
    const unsigned short* Ag = A + (size_t)(bm + srow) * 2048 + sw8 * 8;
    const unsigned short* Bg = BT + (size_t)(bn + srow) * 2048 + sw8 * 8;
    unsigned short* Asl = As + wave * 512;        // + i*2048 per call
    unsigned short* Bsl = Bs + wave * 512;

    f32x4 acc[4][4] = {};

    for (int k0 = 0; k0 < 2048; k0 += 64) {
#pragma unroll
        for (int i = 0; i < 4; i++) {
            glds16(Ag + (size_t)(32 * i) * 2048 + k0, Asl + i * 2048);
            glds16(Bg + (size_t)(32 * i) * 2048 + k0, Bsl + i * 2048);
        }
        __syncthreads();
#pragma unroll
        for (int ks = 0; ks < 2; ks++) {
            bf16x8 af[4], bfr[4];
#pragma unroll
            for (int mt = 0; mt < 4; mt++) {
                const int row = wm + 16 * mt + l15;
                af[mt] = __builtin_bit_cast(bf16x8,
                    *(const u32x4*)&As[row * 64 + (((quad + 4 * ks) ^ (row & 7)) * 8)]);
            }
#pragma unroll
            for (int nt = 0; nt < 4; nt++) {
                const int row = wn + 16 * nt + l15;
                bfr[nt] = __builtin_bit_cast(bf16x8,
                    *(const u32x4*)&Bs[row * 64 + (((quad + 4 * ks) ^ (row & 7)) * 8)]);
            }
#pragma unroll
            for (int mt = 0; mt < 4; mt++)
#pragma unroll
                for (int nt = 0; nt < 4; nt++)
                    acc[mt][nt] = MFMA16(af[mt], bfr[nt], acc[mt][nt]);
        }
        __syncthreads();
    }

    // fused RoPE (cols < 2560 = Q|K), pairwise via shfl; then bf16 store
#pragma unroll
    for (int mt = 0; mt < 4; mt++) {
#pragma unroll
        for (int nt = 0; nt < 4; nt++) {
            const int col = bn + wn + 16 * nt + l15;
            if (col < 2560) {  // 16-aligned boundary -> wave-uniform branch
                const int i = (col & 63) >> 1;
                const float inv = exp2f(-0.41524101186092036f * (float)i);
                const float sign = (col & 1) ? 1.0f : -1.0f;
#pragma unroll
                for (int r = 0; r < 4; r++) {
                    const int row = bm + wm + 16 * mt + quad * 4 + r;
                    float sn, cs;
                    __sincosf((float)row * inv, &sn, &cs);
                    const float partner = __shfl_xor(acc[mt][nt][r], 1, 64);
                    acc[mt][nt][r] = acc[mt][nt][r] * cs + sign * partner * sn;
                }
            }
#pragma unroll
            for (int r = 0; r < 4; r++) {
                const int row = bm + wm + 16 * mt + quad * 4 + r;
                C[(size_t)row * 3072 + col] = f2bf(acc[mt][nt][r]);
            }
        }
    }
}

// ---------------------------------------------------------------------------
// GEMM: C[M][N] = A[M][K] @ BT[N][K]^T (bf16 in, fp32 accum), m97 structure,
// BK=128; used for out-proj (BM=64: 512 blocks = 2/CU).
// ---------------------------------------------------------------------------
template <int BM, bool ROPE>
__global__ __launch_bounds__(256) void gemm_bt(const unsigned short* __restrict__ A,
                                               const unsigned short* __restrict__ BT,
                                               void* __restrict__ Cv,
                                               int K, int lda, int ldb, int ldc,
                                               int out_f32) {
    constexpr int MT = BM / 32;
    constexpr int ACALLS = BM / 16;   // 4KB-chunks for A tile
    __shared__ __align__(16) unsigned short As[BM * 128];
    __shared__ __align__(16) unsigned short Bs[128 * 128];

    const int tid = threadIdx.x;
    const int lane = tid & 63;
    const int wave = tid >> 6;
    const int quad = lane >> 4;
    const int l15 = lane & 15;
    const int bm = blockIdx.x * BM;
    const int bn = blockIdx.y * 128;
    const int wm = (wave & 1) * (BM / 2);
    const int wn = (wave >> 1) * 64;

    // staging: call i covers rows 16i..16i+16; lane row-in-call = wave*4 + (lane>>4)
    const int srow = wave * 4 + (lane >> 4);          // 0..15
    const int sw = (lane & 15) ^ (srow & 7);          // swizzled chunk 0..15
    const unsigned short* Ag = A + (size_t)(bm + srow) * lda + sw * 8;
    const unsigned short* Bg = BT + (size_t)(bn + srow) * ldb + sw * 8;
    unsigned short* Asl = As + wave * 512;            // + i*2048 per call
    unsigned short* Bsl = Bs + wave * 512;

    f32x4 acc[MT][4] = {};

    for (int k0 = 0; k0 < K; k0 += 128) {
#pragma unroll
        for (int i = 0; i < ACALLS; i++)
            glds16(Ag + (size_t)(16 * i) * lda + k0, Asl + i * 2048);
#pragma unroll
        for (int i = 0; i < 8; i++)
            glds16(Bg + (size_t)(16 * i) * ldb + k0, Bsl + i * 2048);
        __syncthreads();
#pragma unroll
        for (int ks = 0; ks < 4; ks++) {
            bf16x8 af[MT], bfr[4];
#pragma unroll
            for (int mt = 0; mt < MT; mt++) {
                const int row = wm + 16 * mt + l15;
                af[mt] = __builtin_bit_cast(bf16x8,
                    *(const u32x4*)&As[row * 128 + (((quad + 4 * ks) ^ (row & 7)) * 8)]);
            }
#pragma unroll
            for (int nt = 0; nt < 4; nt++) {
                const int row = wn + 16 * nt + l15;
                bfr[nt] = __builtin_bit_cast(bf16x8,
                    *(const u32x4*)&Bs[row * 128 + (((quad + 4 * ks) ^ (row & 7)) * 8)]);
            }
#pragma unroll
            for (int mt = 0; mt < MT; mt++)
#pragma unroll
                for (int nt = 0; nt < 4; nt++)
                    acc[mt][nt] = MFMA16(af[mt], bfr[nt], acc[mt][nt]);
        }
        __syncthreads();
    }

    if (ROPE) {
#pragma unroll
        for (int mt = 0; mt < MT; mt++) {
#pragma unroll
            for (int nt = 0; nt < 4; nt++) {
                const int col = bn + wn + 16 * nt + l15;
                if (col < 2560) {
                    const int i = (col & 63) >> 1;
                    const float inv = exp2f(-0.41524101186092036f * (float)i);
                    const float sign = (col & 1) ? 1.0f : -1.0f;
#pragma unroll
                    for (int r = 0; r < 4; r++) {
                        const int row = bm + wm + 16 * mt + quad * 4 + r;
                        float sn, cs;
                        __sincosf((float)row * inv, &sn, &cs);
                        const float partner = __shfl_xor(acc[mt][nt][r], 1, 64);
                        acc[mt][nt][r] = acc[mt][nt][r] * cs + sign * partner * sn;
                    }
                }
            }
        }
    }

    // epilogue: C/D layout col = l15, row = quad*4 + r
#pragma unroll
    for (int mt = 0; mt < MT; mt++) {
#pragma unroll
        for (int nt = 0; nt < 4; nt++) {
#pragma unroll
            for (int r = 0; r < 4; r++) {
                const int row = bm + wm + 16 * mt + quad * 4 + r;
                const int col = bn + wn + 16 * nt + l15;
                if (out_f32)
                    ((float*)Cv)[(size_t)row * ldc + col] = acc[mt][nt][r];
                else
                    ((unsigned short*)Cv)[(size_t)row * ldc + col] = f2bf(acc[mt][nt][r]);
            }
        }
    }
}

// ---------------------------------------------------------------------------
// Flash attention, S^T-trick + fixed-max softmax + MFMA row-sum (P @ ones).
// Block = (64 q rows, head); 4 waves, wave owns 16 q rows (1 m-tile).
// Grid (32,32) = 1024 blocks. Wait-bound diagnosis (3 null experiments,
// all pipes <30% busy): the per-iter serial chain was (a) vmcnt(0) drain
// at the staging barrier and (b) TWO sequential QK->exp->LDS-P-roundtrip->PV
// chains. Fixes here, at CONSTANT barrier count (32):
//  - K/V double-buffered (KVBLK stays 128): STAGE(t+1) issued at iter top,
//    s_waitcnt vmcnt(8) + raw s_barrier -> next tile stays in flight.
//  - kh phases batched: QK both halves (st[8]) -> one 32-exp softmax batch
//    -> ONE P round-trip (8 stores, 4 reads) -> rowsum+PV both halves.
// LDS 32K(K)+32K(V)+16K(St) = 80KB -> 2 blocks/CU (proven ~= 4 blocks/CU).
// qkv: [2048][3072] bf16 (Q|K|V, RoPE applied); vt: [512][2048] = V^T.
// ---------------------------------------------------------------------------
__global__ __launch_bounds__(256) void attn_kernel(const unsigned short* __restrict__ qkv,
                                                   const unsigned short* __restrict__ vt,
                                                   unsigned short* __restrict__ attn_out) {
    const int qb = blockIdx.x;
    const int h = blockIdx.y;
    const int kvh = h >> 2;
    const int tid = threadIdx.x;
    const int lane = tid & 63;
    const int wave = tid >> 6;
    const int quad = lane >> 4;
    const int l15 = lane & 15;
    const int l7 = l15 & 7;
    const int w0 = qb * 64 + wave * 16;

    __shared__ __align__(16) unsigned short Ks[2][128 * 64];  // [buf][kv 128][d 64]
    __shared__ __align__(16) unsigned short Vs[2][64 * 128];  // [buf][d 64][kv 128]
    __shared__ __align__(16) unsigned short St[4][16][128];   // per-wave P (q x 128kv), XOR-swizzled
    unsigned short (*Sw)[128] = St[wave];

    // K staging map (64-u16 rows, 8 chunk slots)
    const int srow = wave * 8 + (lane >> 3);
    const int swK = (lane & 7) ^ (srow & 7);
    const unsigned short* Kg = qkv + 2048 + kvh * 64 + swK * 8;  // + (kbase+srow+32i)*3072
    unsigned short* Ksb = &Ks[0][0] + wave * 512;                // + b*8192 + i*2048
    // V staging map (128-u16 rows, 16 chunk slots)
    const int vrow = wave * 4 + (lane >> 4);
    const int swV = (lane & 15) ^ (vrow & 7);
    const unsigned short* Vg = vt + (size_t)(kvh * 64 + vrow) * 2048 + swV * 8;  // + 16i*2048 + kbase
    unsigned short* Vsb = &Vs[0][0] + wave * 512;                // + b*8192 + i*2048

    // Q fragments (MFMA B-operand: n=q=l15, k=quad*8+j),
    // pre-scaled by log2e/8 (shift-invariant softmax, no bias needed).
    const float QSCALE = 0.18033688011111093f;  // 0.125 * log2(e)
    bf16x8 qf[2];
#pragma unroll
    for (int ks = 0; ks < 2; ks++) {
        u32x4 raw = *(const u32x4*)&qkv[(size_t)(w0 + l15) * 3072 + h * 64 + quad * 8 + 32 * ks];
        u16x8 t = __builtin_bit_cast(u16x8, raw);
#pragma unroll
        for (int j = 0; j < 8; j++) t[j] = f2bf(bf2f(t[j]) * QSCALE);
        qf[ks] = __builtin_bit_cast(bf16x8, t);
    }

    bf16x8 ones;
#pragma unroll
    for (int j = 0; j < 8; j++) ones[j] = (__bf16)1.0f;

    f32x4 acc_o[4] = {};
    f32x4 acc_l = {};

#define STAGE_KV(kt, b) do {                                                      \
        const size_t kb_ = (size_t)(kt) * 128;                                    \
        _Pragma("unroll")                                                         \
        for (int i_ = 0; i_ < 4; i_++) {                                          \
            glds16(Kg + (kb_ + srow + 32 * i_) * 3072, Ksb + (b) * 8192 + i_ * 2048); \
            glds16(Vg + (size_t)(16 * i_) * 2048 + kb_, Vsb + (b) * 8192 + i_ * 2048); \
        }                                                                         \
    } while (0)

    STAGE_KV(0, 0);

    for (int kt = 0; kt < 16; kt++) {
        const int cur = kt & 1;
        if (kt < 15) {
            STAGE_KV(kt + 1, cur ^ 1);
            // wait own 8 loads of buf[cur]; keep next tile's 8 in flight
            asm volatile("s_waitcnt vmcnt(8)" ::: "memory");
        } else {
            asm volatile("s_waitcnt vmcnt(0)" ::: "memory");
        }
        __builtin_amdgcn_s_barrier();   // all waves' cur-tile loads landed

        const unsigned short* Kb = Ks[cur];
        const unsigned short* Vb = Vs[cur];

        // S^T = K Q^T for ALL 128 kv rows: A = K-frag (m=kv), B = Q-frag (n=q)
        f32x4 st[8] = {};
        __builtin_amdgcn_s_setprio(1);
#pragma unroll
        for (int kh = 0; kh < 2; kh++)
#pragma unroll
            for (int n = 0; n < 4; n++) {
                const int row = kh * 64 + 16 * n + l15;
                const bf16x8 kf0 = __builtin_bit_cast(bf16x8,
                    *(const u32x4*)&Kb[row * 64 + ((quad ^ l7) * 8)]);
                const bf16x8 kf1 = __builtin_bit_cast(bf16x8,
                    *(const u32x4*)&Kb[row * 64 + (((quad + 4) ^ l7) * 8)]);
                st[kh * 4 + n] = MFMA16(kf0, qf[0], st[kh * 4 + n]);
                st[kh * 4 + n] = MFMA16(kf1, qf[1], st[kh * 4 + n]);
            }
        __builtin_amdgcn_s_setprio(0);

        // softmax batch: p = exp2(st), 32 independent exps; lane holds
        // q=l15, kv=kh*64+16n+quad*4+r. St chunk swizzle: phys chunk =
        // kh*8 + ((2n+gq)^l7), payload offset oq.
        const int gq = quad >> 1, oq = (quad & 1) * 4;
#pragma unroll
        for (int kh = 0; kh < 2; kh++)
#pragma unroll
            for (int n = 0; n < 4; n++) {
                u16x4 pk;
#pragma unroll
                for (int r = 0; r < 4; r++)
                    pk[r] = f2bf(exp2f(st[kh * 4 + n][r]));
                *(u16x4*)&Sw[l15][((kh * 8 + ((2 * n + gq) ^ l7)) << 3) + oq] = pk;
            }

        // P A-frags (m=q=l15, k=kv=kh*32+quad*8+j) from swizzled Sw rows
        bf16x8 pf[2][2];
#pragma unroll
        for (int kh = 0; kh < 2; kh++) {
            pf[kh][0] = __builtin_bit_cast(bf16x8,
                *(const u32x4*)&Sw[l15][(kh * 8 + (quad ^ l7)) << 3]);
            pf[kh][1] = __builtin_bit_cast(bf16x8,
                *(const u32x4*)&Sw[l15][(kh * 8 + ((quad + 4) ^ l7)) << 3]);
        }

        __builtin_amdgcn_s_setprio(1);
        // row sums: acc_l += P @ ones  (C-rows match acc_o's rows)
#pragma unroll
        for (int kh = 0; kh < 2; kh++) {
            acc_l = MFMA16(pf[kh][0], ones, acc_l);
            acc_l = MFMA16(pf[kh][1], ones, acc_l);
        }

        // O += P @ V : B = V^T rows (n=d=l15, k=kv)
#pragma unroll
        for (int kh = 0; kh < 2; kh++)
#pragma unroll
            for (int nt = 0; nt < 4; nt++) {
                const int row = 16 * nt + l15;
                const int c0 = kh * 8 + (quad ^ l7);
                const int c1 = kh * 8 + ((quad + 4) ^ l7);
                const bf16x8 vf0 = __builtin_bit_cast(bf16x8, *(const u32x4*)&Vb[row * 128 + c0 * 8]);
                const bf16x8 vf1 = __builtin_bit_cast(bf16x8, *(const u32x4*)&Vb[row * 128 + c1 * 8]);
                acc_o[nt] = MFMA16(pf[kh][0], vf0, acc_o[nt]);
                acc_o[nt] = MFMA16(pf[kh][1], vf1, acc_o[nt]);
            }
        __builtin_amdgcn_s_setprio(0);

        __builtin_amdgcn_s_barrier();   // reads of buf[cur] done -> kt+1 may overwrite buf[cur^1]
    }
#undef STAGE_KV

    // epilogue: acc_o and acc_l share lane layout q=quad*4+r, d=16nt+l15
    float linv[4];
#pragma unroll
    for (int r = 0; r < 4; r++) linv[r] = 1.0f / acc_l[r];
#pragma unroll
    for (int nt = 0; nt < 4; nt++)
#pragma unroll
        for (int r = 0; r < 4; r++)
            attn_out[(size_t)(w0 + quad * 4 + r) * 2048 + h * 64 + 16 * nt + l15] =
                f2bf(acc_o[nt][r] * linv[r]);
}

// ---------------------------------------------------------------------------
extern "C" void kernel_launch(void* const* d_in, const int* in_sizes, int n_in,
                              void* d_out, int out_size, void* d_ws, size_t ws_size,
                              hipStream_t stream) {
    (void)in_sizes; (void)n_in; (void)out_size; (void)ws_size;

    const float* X  = (const float*)d_in[0];
    const float* Wq = (const float*)d_in[1];
    const float* Wk = (const float*)d_in[2];
    const float* Wv = (const float*)d_in[3];
    const float* Wo = (const float*)d_in[4];

    // ws (u16): phase1 Xbf[0..4.19M) wqkvT[4.19M..10.49M)
    //           phase2 vt[0..1.05M) attnO[1.05M..5.24M) woT[5.24M..9.44M)
    // qkv parks in d_out (12.6MB of 16.8MB); final GEMM rewrites d_out in f32.
    unsigned short* ws16  = (unsigned short*)d_ws;
    unsigned short* Xbf   = ws16;
    unsigned short* wqkvT = ws16 + (size_t)4194304;
    unsigned short* qkv   = (unsigned short*)d_out;
    unsigned short* vt    = ws16;
    unsigned short* attnO = ws16 + (size_t)1048576;
    unsigned short* woT   = ws16 + (size_t)5242880;

    // X cvt + Wqkv transpose
    prep1<<<10240, 256, 0, stream>>>(X, Wq, Wk, Wv, Xbf, wqkvT);

    // QKV = X @ [Wq|Wk|Wv] -> bf16 in d_out, RoPE fused (m97 128^2 BK=64)
    gemm128_qkv<<<dim3(16, 24), 256, 0, stream>>>(Xbf, wqkvT, qkv);

    // Wo transpose (into dead wqkvT region) + V^T (into dead Xbf region)
    prep2<<<5120, 256, 0, stream>>>(Wo, qkv, woT, vt);

    // attention -> attnO (bf16), 64 q-rows per block
    attn_kernel<<<dim3(32, 32), 256, 0, stream>>>(qkv, vt, attnO);

    // out = attnO @ Wo -> f32 into d_out (overwrites dead qkv)
    gemm_bt<64, false><<<dim3(32, 16), 256, 0, stream>>>(attnO, woT, (void*)d_out, 2048, 2048, 2048, 2048, 1);
}

// Round 5
// 232.810 us; speedup vs baseline: 1.0483x; 1.0483x over previous
//
#include <hip/hip_runtime.h>

typedef __bf16 bf16x8 __attribute__((ext_vector_type(8)));
typedef float f32x4 __attribute__((ext_vector_type(4)));
typedef unsigned short u16x4 __attribute__((ext_vector_type(4)));
typedef unsigned short u16x8 __attribute__((ext_vector_type(8)));
typedef unsigned int u32x4 __attribute__((ext_vector_type(4)));

__device__ __forceinline__ float bf2f(unsigned short h) {
    union { unsigned int u; float f; } v;
    v.u = ((unsigned int)h) << 16;
    return v.f;
}
__device__ __forceinline__ unsigned short f2bf(float f) {
    return __builtin_bit_cast(unsigned short, (__bf16)f);  // native v_cvt, RNE
}
// async global->LDS, 16B per lane; LDS dest = wave-uniform base + lane*16
__device__ __forceinline__ void glds16(const unsigned short* g, unsigned short* l) {
    __builtin_amdgcn_global_load_lds((__attribute__((address_space(1))) void*)g,
                                     (__attribute__((address_space(3))) void*)l,
                                     16, 0, 0);
}

#define MFMA16(a, b, c) __builtin_amdgcn_mfma_f32_16x16x32_bf16((a), (b), (c), 0, 0, 0)

// ---------------------------------------------------------------------------
// prep1: X f32->bf16 cvt (blocks 0..4095, float4 wide) + merged Wq|Wk|Wv
// f32->bf16 transpose into wqkvT[3072][2048] (blocks 4096..5631).
// Transpose uses 64x64 tiles with float4 loads (16B/lane) and u16x4 stores
// (8B/lane) -- the old 32x32 scalar-f32 version was 4B/lane (G13 violation).
// ---------------------------------------------------------------------------
__global__ __launch_bounds__(256) void prep1(const float* __restrict__ X,
                                             const float* __restrict__ Wq,
                                             const float* __restrict__ Wk,
                                             const float* __restrict__ Wv,
                                             unsigned short* __restrict__ Xbf,
                                             unsigned short* __restrict__ wqkvT) {
    const int b = blockIdx.x;
    const int tid = threadIdx.x;
    if (b < 4096) {
        const int i = (b * 256 + tid) * 4;
        const float4 v = *(const float4*)(X + i);
        u16x4 o;
        o[0] = f2bf(v.x); o[1] = f2bf(v.y); o[2] = f2bf(v.z); o[3] = f2bf(v.w);
        *(u16x4*)(Xbf + i) = o;
        return;
    }
    __shared__ __align__(16) unsigned short Lt[64][72];  // 9216B, 16B-aligned rows
    const int b2 = b - 4096;                 // 0..1535
    const int kb = (b2 & 31) * 64;           // k-dim base (rows of W), 32 tiles
    const int nb = (b2 >> 5) * 64;           // fused out-col base 0..3071, 48 tiles
    const float* src; int scol, sld;
    if (nb < 2048)      { src = Wq; scol = nb;        sld = 2048; }
    else if (nb < 2560) { src = Wk; scol = nb - 2048; sld = 512;  }
    else                { src = Wv; scol = nb - 2560; sld = 512;  }
    const int r16 = tid >> 4, c4 = tid & 15;
#pragma unroll
    for (int i = 0; i < 4; i++) {
        const int row = r16 + 16 * i;
        const float4 v = *(const float4*)(src + (size_t)(kb + row) * sld + scol + c4 * 4);
        u16x4 o;
        o[0] = f2bf(v.x); o[1] = f2bf(v.y); o[2] = f2bf(v.z); o[3] = f2bf(v.w);
        *(u16x4*)&Lt[row][c4 * 4] = o;
    }
    __syncthreads();
#pragma unroll
    for (int i = 0; i < 4; i++) {
        const int orow = r16 + 16 * i;       // n-dim within tile
        u16x4 o;
#pragma unroll
        for (int j = 0; j < 4; j++) o[j] = Lt[c4 * 4 + j][orow];
        *(u16x4*)&wqkvT[(size_t)(nb + orow) * 2048 + kb + c4 * 4] = o;
    }
}

// ---------------------------------------------------------------------------
// prep2 (post-QKV GEMM): Wo f32->bf16 transpose -> woT (blocks 0..1023,
// 64x64 float4 tiles) + V bf16 transpose qkv[:,2560:3072] -> vt[512][2048]
// (blocks 1024..1279, 64x64 u16x8 tiles).
// ---------------------------------------------------------------------------
__global__ __launch_bounds__(256) void prep2(const float* __restrict__ Wo,
                                             const unsigned short* __restrict__ qkv,
                                             unsigned short* __restrict__ woT,
                                             unsigned short* __restrict__ vt) {
    const int b = blockIdx.x;
    const int tid = threadIdx.x;
    __shared__ __align__(16) unsigned short Lt[64][72];
    const int r16 = tid >> 4, c4 = tid & 15;
    if (b < 1024) {
        const int kb = (b & 31) * 64;
        const int nb = (b >> 5) * 64;
#pragma unroll
        for (int i = 0; i < 4; i++) {
            const int row = r16 + 16 * i;
            const float4 v = *(const float4*)(Wo + (size_t)(kb + row) * 2048 + nb + c4 * 4);
            u16x4 o;
            o[0] = f2bf(v.x); o[1] = f2bf(v.y); o[2] = f2bf(v.z); o[3] = f2bf(v.w);
            *(u16x4*)&Lt[row][c4 * 4] = o;
        }
        __syncthreads();
#pragma unroll
        for (int i = 0; i < 4; i++) {
            const int orow = r16 + 16 * i;
            u16x4 o;
#pragma unroll
            for (int j = 0; j < 4; j++) o[j] = Lt[c4 * 4 + j][orow];
            *(u16x4*)&woT[(size_t)(nb + orow) * 2048 + kb + c4 * 4] = o;
        }
    } else {
        const int b2 = b - 1024;             // 0..255
        const int bx = (b2 & 7) * 64;        // d-col base in V (0..511), 8 tiles
        const int by = (b2 >> 3) * 64;       // s-row base (0..2047), 32 tiles
        const int r32 = tid >> 3, c8 = tid & 7;
#pragma unroll
        for (int i = 0; i < 2; i++) {
            const int row = r32 + 32 * i;    // s within tile
            *(u16x8*)&Lt[row][c8 * 8] =
                *(const u16x8*)&qkv[(size_t)(by + row) * 3072 + 2560 + bx + c8 * 8];
        }
        __syncthreads();
#pragma unroll
        for (int i = 0; i < 4; i++) {
            const int orow = r16 + 16 * i;   // d within tile
            u16x4 o;
#pragma unroll
            for (int j = 0; j < 4; j++) o[j] = Lt[c4 * 4 + j][orow];
            *(u16x4*)&vt[(size_t)(bx + orow) * 2048 + by + c4 * 4] = o;
        }
    }
}

// ---------------------------------------------------------------------------
// gemm128_qkv: QKV = Xbf @ wqkvT^T, m97-exact 128x128 tile BK=64, 4 waves
// 2x2 (64x64/wave), glds16 staging, RoPE fused, bf16 out ldc=3072.
// ---------------------------------------------------------------------------
__global__ __launch_bounds__(256) void gemm128_qkv(const unsigned short* __restrict__ A,
                                                   const unsigned short* __restrict__ BT,
                                                   unsigned short* __restrict__ C) {
    __shared__ __align__(16) unsigned short As[128 * 64];
    __shared__ __align__(16) unsigned short Bs[128 * 64];

    const int tid = threadIdx.x;
    const int lane = tid & 63;
    const int wave = tid >> 6;
    const int quad = lane >> 4;
    const int l15 = lane & 15;
    const int bm = blockIdx.x * 128;
    const int bn = blockIdx.y * 128;
    const int wm = (wave & 1) * 64;
    const int wn = (wave >> 1) * 64;

    const int srow = wave * 8 + (lane >> 3);      // 0..31 (+32 per call)
    const int sw8 = (lane & 7) ^ (srow & 7);
    const unsigned short* Ag = A + (size_t)(bm + srow) * 2048 + sw8 * 8;
    const unsigned short* Bg = BT + (size_t)(bn + srow) * 2048 + sw8 * 8;
    unsigned short* Asl = As + wave * 512;        // + i*2048 per call
    unsigned short* Bsl = Bs + wave * 512;

    f32x4 acc[4][4] = {};

    for (int k0 = 0; k0 < 2048; k0 += 64) {
#pragma unroll
        for (int i = 0; i < 4; i++) {
            glds16(Ag + (size_t)(32 * i) * 2048 + k0, Asl + i * 2048);
            glds16(Bg + (size_t)(32 * i) * 2048 + k0, Bsl + i * 2048);
        }
        __syncthreads();
#pragma unroll
        for (int ks = 0; ks < 2; ks++) {
            bf16x8 af[4], bfr[4];
#pragma unroll
            for (int mt = 0; mt < 4; mt++) {
                const int row = wm + 16 * mt + l15;
                af[mt] = __builtin_bit_cast(bf16x8,
                    *(const u32x4*)&As[row * 64 + (((quad + 4 * ks) ^ (row & 7)) * 8)]);
            }
#pragma unroll
            for (int nt = 0; nt < 4; nt++) {
                const int row = wn + 16 * nt + l15;
                bfr[nt] = __builtin_bit_cast(bf16x8,
                    *(const u32x4*)&Bs[row * 64 + (((quad + 4 * ks) ^ (row & 7)) * 8)]);
            }
#pragma unroll
            for (int mt = 0; mt < 4; mt++)
#pragma unroll
                for (int nt = 0; nt < 4; nt++)
                    acc[mt][nt] = MFMA16(af[mt], bfr[nt], acc[mt][nt]);
        }
        __syncthreads();
    }

    // fused RoPE (cols < 2560 = Q|K), pairwise via shfl; then bf16 store
#pragma unroll
    for (int mt = 0; mt < 4; mt++) {
#pragma unroll
        for (int nt = 0; nt < 4; nt++) {
            const int col = bn + wn + 16 * nt + l15;
            if (col < 2560) {  // 16-aligned boundary -> wave-uniform branch
                const int i = (col & 63) >> 1;
                const float inv = exp2f(-0.41524101186092036f * (float)i);
                const float sign = (col & 1) ? 1.0f : -1.0f;
#pragma unroll
                for (int r = 0; r < 4; r++) {
                    const int row = bm + wm + 16 * mt + quad * 4 + r;
                    float sn, cs;
                    __sincosf((float)row * inv, &sn, &cs);
                    const float partner = __shfl_xor(acc[mt][nt][r], 1, 64);
                    acc[mt][nt][r] = acc[mt][nt][r] * cs + sign * partner * sn;
                }
            }
#pragma unroll
            for (int r = 0; r < 4; r++) {
                const int row = bm + wm + 16 * mt + quad * 4 + r;
                C[(size_t)row * 3072 + col] = f2bf(acc[mt][nt][r]);
            }
        }
    }
}

// ---------------------------------------------------------------------------
// GEMM: C[M][N] = A[M][K] @ BT[N][K]^T (bf16 in, fp32 accum), m97 structure,
// BK=128; used for out-proj (BM=64: 512 blocks = 2/CU).
// ---------------------------------------------------------------------------
template <int BM, bool ROPE>
__global__ __launch_bounds__(256) void gemm_bt(const unsigned short* __restrict__ A,
                                               const unsigned short* __restrict__ BT,
                                               void* __restrict__ Cv,
                                               int K, int lda, int ldb, int ldc,
                                               int out_f32) {
    constexpr int MT = BM / 32;
    constexpr int ACALLS = BM / 16;   // 4KB-chunks for A tile
    __shared__ __align__(16) unsigned short As[BM * 128];
    __shared__ __align__(16) unsigned short Bs[128 * 128];

    const int tid = threadIdx.x;
    const int lane = tid & 63;
    const int wave = tid >> 6;
    const int quad = lane >> 4;
    const int l15 = lane & 15;
    const int bm = blockIdx.x * BM;
    const int bn = blockIdx.y * 128;
    const int wm = (wave & 1) * (BM / 2);
    const int wn = (wave >> 1) * 64;

    // staging: call i covers rows 16i..16i+16; lane row-in-call = wave*4 + (lane>>4)
    const int srow = wave * 4 + (lane >> 4);          // 0..15
    const int sw = (lane & 15) ^ (srow & 7);          // swizzled chunk 0..15
    const unsigned short* Ag = A + (size_t)(bm + srow) * lda + sw * 8;
    const unsigned short* Bg = BT + (size_t)(bn + srow) * ldb + sw * 8;
    unsigned short* Asl = As + wave * 512;            // + i*2048 per call
    unsigned short* Bsl = Bs + wave * 512;

    f32x4 acc[MT][4] = {};

    for (int k0 = 0; k0 < K; k0 += 128) {
#pragma unroll
        for (int i = 0; i < ACALLS; i++)
            glds16(Ag + (size_t)(16 * i) * lda + k0, Asl + i * 2048);
#pragma unroll
        for (int i = 0; i < 8; i++)
            glds16(Bg + (size_t)(16 * i) * ldb + k0, Bsl + i * 2048);
        __syncthreads();
#pragma unroll
        for (int ks = 0; ks < 4; ks++) {
            bf16x8 af[MT], bfr[4];
#pragma unroll
            for (int mt = 0; mt < MT; mt++) {
                const int row = wm + 16 * mt + l15;
                af[mt] = __builtin_bit_cast(bf16x8,
                    *(const u32x4*)&As[row * 128 + (((quad + 4 * ks) ^ (row & 7)) * 8)]);
            }
#pragma unroll
            for (int nt = 0; nt < 4; nt++) {
                const int row = wn + 16 * nt + l15;
                bfr[nt] = __builtin_bit_cast(bf16x8,
                    *(const u32x4*)&Bs[row * 128 + (((quad + 4 * ks) ^ (row & 7)) * 8)]);
            }
#pragma unroll
            for (int mt = 0; mt < MT; mt++)
#pragma unroll
                for (int nt = 0; nt < 4; nt++)
                    acc[mt][nt] = MFMA16(af[mt], bfr[nt], acc[mt][nt]);
        }
        __syncthreads();
    }

    if (ROPE) {
#pragma unroll
        for (int mt = 0; mt < MT; mt++) {
#pragma unroll
            for (int nt = 0; nt < 4; nt++) {
                const int col = bn + wn + 16 * nt + l15;
                if (col < 2560) {
                    const int i = (col & 63) >> 1;
                    const float inv = exp2f(-0.41524101186092036f * (float)i);
                    const float sign = (col & 1) ? 1.0f : -1.0f;
#pragma unroll
                    for (int r = 0; r < 4; r++) {
                        const int row = bm + wm + 16 * mt + quad * 4 + r;
                        float sn, cs;
                        __sincosf((float)row * inv, &sn, &cs);
                        const float partner = __shfl_xor(acc[mt][nt][r], 1, 64);
                        acc[mt][nt][r] = acc[mt][nt][r] * cs + sign * partner * sn;
                    }
                }
            }
        }
    }

    // epilogue: C/D layout col = l15, row = quad*4 + r
#pragma unroll
    for (int mt = 0; mt < MT; mt++) {
#pragma unroll
        for (int nt = 0; nt < 4; nt++) {
#pragma unroll
            for (int r = 0; r < 4; r++) {
                const int row = bm + wm + 16 * mt + quad * 4 + r;
                const int col = bn + wn + 16 * nt + l15;
                if (out_f32)
                    ((float*)Cv)[(size_t)row * ldc + col] = acc[mt][nt][r];
                else
                    ((unsigned short*)Cv)[(size_t)row * ldc + col] = f2bf(acc[mt][nt][r]);
            }
        }
    }
}

// ---------------------------------------------------------------------------
// Flash attention -- REVERTED to the round-0 best-measured structure
// (73.5us): block = (128 q rows, head), 4 waves x 32 q rows, serial
// KVBLK=128 single-buffer staging, St[4][32][72]. Kept free improvements:
// Q pre-scaled by log2e/8 (shift-invariant softmax, no fmaf bias) and
// s_setprio(1) around MFMA clusters. Grid (16,32) = 512 blocks.
// 4 structural experiments (dbuf prefetch x2, 4-blk/CU occupancy, batched
// phases) all measured null-to-negative vs this config.
// qkv: [2048][3072] bf16 (Q|K|V, RoPE applied); vt: [512][2048] = V^T.
// ---------------------------------------------------------------------------
__global__ __launch_bounds__(256) void attn_kernel(const unsigned short* __restrict__ qkv,
                                                   const unsigned short* __restrict__ vt,
                                                   unsigned short* __restrict__ attn_out) {
    const int qb = blockIdx.x;
    const int h = blockIdx.y;
    const int kvh = h >> 2;
    const int tid = threadIdx.x;
    const int lane = tid & 63;
    const int wave = tid >> 6;
    const int quad = lane >> 4;
    const int l15 = lane & 15;
    const int w0 = qb * 128 + wave * 32;

    __shared__ __align__(16) unsigned short Ks[128 * 64];   // K rows x 64 d
    __shared__ __align__(16) unsigned short Vs[64 * 128];   // V^T: 64 d x 128 kv
    __shared__ __align__(16) unsigned short St[4][32][72];  // per-wave P (q x kv)
    unsigned short (*Sw)[72] = St[wave];

    // K staging map (64-u16 rows, 8 chunk slots)
    const int srow = wave * 8 + (lane >> 3);
    const int swK = (lane & 7) ^ (srow & 7);
    const unsigned short* Kg = qkv + 2048 + kvh * 64 + swK * 8;  // + (kbase+srow+32i)*3072
    unsigned short* Ksl = Ks + wave * 512;
    // V staging map (128-u16 rows, 16 chunk slots)
    const int vrow = wave * 4 + (lane >> 4);
    const int swV = (lane & 15) ^ (vrow & 7);
    const unsigned short* Vg = vt + (size_t)(kvh * 64 + vrow) * 2048 + swV * 8;  // + 16i*2048 + kbase
    unsigned short* Vsl = Vs + wave * 512;

    // Q fragments (MFMA B-operand: n=q=l15, k=quad*8+j), pre-scaled by
    // log2e/8 (shift-invariant softmax: no exponent bias needed).
    const float QSCALE = 0.18033688011111093f;  // 0.125 * log2(e)
    bf16x8 qf[2][2];
#pragma unroll
    for (int mt = 0; mt < 2; mt++)
#pragma unroll
        for (int ks = 0; ks < 2; ks++) {
            u32x4 raw = *(const u32x4*)&qkv[(size_t)(w0 + 16 * mt + l15) * 3072 + h * 64 + quad * 8 + 32 * ks];
            u16x8 t = __builtin_bit_cast(u16x8, raw);
#pragma unroll
            for (int j = 0; j < 8; j++) t[j] = f2bf(bf2f(t[j]) * QSCALE);
            qf[mt][ks] = __builtin_bit_cast(bf16x8, t);
        }

    bf16x8 ones;
#pragma unroll
    for (int j = 0; j < 8; j++) ones[j] = (__bf16)1.0f;

    f32x4 acc_o[2][4] = {};
    f32x4 acc_l[2] = {};

    for (int kb2 = 0; kb2 < 16; kb2++) {
        const int kbase = kb2 * 128;
#pragma unroll
        for (int i = 0; i < 4; i++) {
            glds16(Kg + (size_t)(kbase + srow + 32 * i) * 3072, Ksl + i * 2048);
            glds16(Vg + (size_t)(16 * i) * 2048 + kbase, Vsl + i * 2048);
        }
        __syncthreads();

#pragma unroll
        for (int kh = 0; kh < 2; kh++) {
            // S^T = K Q^T : A = K-frag (m=kv), B = Q-frag (n=q)
            f32x4 st[2][4] = {};
            __builtin_amdgcn_s_setprio(1);
#pragma unroll
            for (int n = 0; n < 4; n++) {
                const int row = kh * 64 + 16 * n + l15;
                const bf16x8 kf0 = __builtin_bit_cast(bf16x8,
                    *(const u32x4*)&Ks[row * 64 + ((quad ^ (l15 & 7)) * 8)]);
                const bf16x8 kf1 = __builtin_bit_cast(bf16x8,
                    *(const u32x4*)&Ks[row * 64 + (((quad + 4) ^ (l15 & 7)) * 8)]);
#pragma unroll
                for (int mt = 0; mt < 2; mt++) {
                    st[mt][n] = MFMA16(kf0, qf[mt][0], st[mt][n]);
                    st[mt][n] = MFMA16(kf1, qf[mt][1], st[mt][n]);
                }
            }
            __builtin_amdgcn_s_setprio(0);

            // p = exp2(st); lane holds q=l15, kv=16n+quad*4+r
            // -> contiguous b64 store into Sw[q][kv]
#pragma unroll
            for (int mt = 0; mt < 2; mt++)
#pragma unroll
                for (int n = 0; n < 4; n++) {
                    u16x4 pk;
#pragma unroll
                    for (int r = 0; r < 4; r++)
                        pk[r] = f2bf(exp2f(st[mt][n][r]));
                    *(u16x4*)&Sw[16 * mt + l15][16 * n + quad * 4] = pk;
                }

            // P A-frags (m=q=l15, k=kv=quad*8+j) straight from Sw rows
            bf16x8 pf[2][2];
#pragma unroll
            for (int mt = 0; mt < 2; mt++) {
                pf[mt][0] = __builtin_bit_cast(bf16x8, *(const u32x4*)&Sw[16 * mt + l15][quad * 8]);
                pf[mt][1] = __builtin_bit_cast(bf16x8, *(const u32x4*)&Sw[16 * mt + l15][quad * 8 + 32]);
            }

            __builtin_amdgcn_s_setprio(1);
            // row sums: acc_l[mt] += P @ ones  (C-rows match acc_o's rows)
#pragma unroll
            for (int mt = 0; mt < 2; mt++) {
                acc_l[mt] = MFMA16(pf[mt][0], ones, acc_l[mt]);
                acc_l[mt] = MFMA16(pf[mt][1], ones, acc_l[mt]);
            }

            // O += P @ V : B = V^T rows (n=d=l15, k=kv)
#pragma unroll
            for (int nt = 0; nt < 4; nt++) {
                const int row = 16 * nt + l15;
                const int c0 = kh * 8 + (quad ^ (l15 & 7));
                const int c1 = kh * 8 + ((quad + 4) ^ (l15 & 7));
                const bf16x8 vf0 = __builtin_bit_cast(bf16x8, *(const u32x4*)&Vs[row * 128 + c0 * 8]);
                const bf16x8 vf1 = __builtin_bit_cast(bf16x8, *(const u32x4*)&Vs[row * 128 + c1 * 8]);
#pragma unroll
                for (int mt = 0; mt < 2; mt++) {
                    acc_o[mt][nt] = MFMA16(pf[mt][0], vf0, acc_o[mt][nt]);
                    acc_o[mt][nt] = MFMA16(pf[mt][1], vf1, acc_o[mt][nt]);
                }
            }
            __builtin_amdgcn_s_setprio(0);
        }
        __syncthreads();
    }

    // epilogue: acc_o and acc_l share lane layout q=quad*4+r (+16mt), d=16nt+l15
#pragma unroll
    for (int mt = 0; mt < 2; mt++) {
        float linv[4];
#pragma unroll
        for (int r = 0; r < 4; r++) linv[r] = 1.0f / acc_l[mt][r];
#pragma unroll
        for (int nt = 0; nt < 4; nt++)
#pragma unroll
            for (int r = 0; r < 4; r++)
                attn_out[(size_t)(w0 + 16 * mt + quad * 4 + r) * 2048 + h * 64 + 16 * nt + l15] =
                    f2bf(acc_o[mt][nt][r] * linv[r]);
    }
}

// ---------------------------------------------------------------------------
extern "C" void kernel_launch(void* const* d_in, const int* in_sizes, int n_in,
                              void* d_out, int out_size, void* d_ws, size_t ws_size,
                              hipStream_t stream) {
    (void)in_sizes; (void)n_in; (void)out_size; (void)ws_size;

    const float* X  = (const float*)d_in[0];
    const float* Wq = (const float*)d_in[1];
    const float* Wk = (const float*)d_in[2];
    const float* Wv = (const float*)d_in[3];
    const float* Wo = (const float*)d_in[4];

    // ws (u16): phase1 Xbf[0..4.19M) wqkvT[4.19M..10.49M)
    //           phase2 vt[0..1.05M) attnO[1.05M..5.24M) woT[5.24M..9.44M)
    // qkv parks in d_out (12.6MB of 16.8MB); final GEMM rewrites d_out in f32.
    unsigned short* ws16  = (unsigned short*)d_ws;
    unsigned short* Xbf   = ws16;
    unsigned short* wqkvT = ws16 + (size_t)4194304;
    unsigned short* qkv   = (unsigned short*)d_out;
    unsigned short* vt    = ws16;
    unsigned short* attnO = ws16 + (size_t)1048576;
    unsigned short* woT   = ws16 + (size_t)5242880;

    // X cvt (4096 blocks) + Wqkv 64x64 float4 transpose (1536 blocks)
    prep1<<<5632, 256, 0, stream>>>(X, Wq, Wk, Wv, Xbf, wqkvT);

    // QKV = X @ [Wq|Wk|Wv] -> bf16 in d_out, RoPE fused (m97 128^2 BK=64)
    gemm128_qkv<<<dim3(16, 24), 256, 0, stream>>>(Xbf, wqkvT, qkv);

    // Wo 64x64 float4 transpose (1024 blocks, into dead wqkvT region)
    // + V^T 64x64 u16 transpose (256 blocks, into dead Xbf region)
    prep2<<<1280, 256, 0, stream>>>(Wo, qkv, woT, vt);

    // attention -> attnO (bf16), 128 q-rows per block (round-0 config)
    attn_kernel<<<dim3(16, 32), 256, 0, stream>>>(qkv, vt, attnO);

    // out = attnO @ Wo -> f32 into d_out (overwrites dead qkv)
    gemm_bt<64, false><<<dim3(32, 16), 256, 0, stream>>>(attnO, woT, (void*)d_out, 2048, 2048, 2048, 2048, 1);
}

// Round 6
// 227.103 us; speedup vs baseline: 1.0746x; 1.0251x over previous
//
#include <hip/hip_runtime.h>

typedef __bf16 bf16x8 __attribute__((ext_vector_type(8)));
typedef float f32x4 __attribute__((ext_vector_type(4)));
typedef unsigned short u16x4 __attribute__((ext_vector_type(4)));
typedef unsigned short u16x8 __attribute__((ext_vector_type(8)));
typedef unsigned int u32x4 __attribute__((ext_vector_type(4)));

__device__ __forceinline__ float bf2f(unsigned short h) {
    union { unsigned int u; float f; } v;
    v.u = ((unsigned int)h) << 16;
    return v.f;
}
__device__ __forceinline__ unsigned short f2bf(float f) {
    return __builtin_bit_cast(unsigned short, (__bf16)f);  // native v_cvt, RNE
}
// async global->LDS, 16B per lane; LDS dest = wave-uniform base + lane*16
__device__ __forceinline__ void glds16(const unsigned short* g, unsigned short* l) {
    __builtin_amdgcn_global_load_lds((__attribute__((address_space(1))) void*)g,
                                     (__attribute__((address_space(3))) void*)l,
                                     16, 0, 0);
}

#define MFMA16(a, b, c) __builtin_amdgcn_mfma_f32_16x16x32_bf16((a), (b), (c), 0, 0, 0)

// ---------------------------------------------------------------------------
// prep1: X f32->bf16 cvt (blocks 0..4095, float4 wide) + merged Wq|Wk|Wv
// f32->bf16 transpose into wqkvT[3072][2048] (blocks 4096..5631).
// 64x64 tiles, float4 loads (16B/lane), u16x4 stores (8B/lane).
// ---------------------------------------------------------------------------
__global__ __launch_bounds__(256) void prep1(const float* __restrict__ X,
                                             const float* __restrict__ Wq,
                                             const float* __restrict__ Wk,
                                             const float* __restrict__ Wv,
                                             unsigned short* __restrict__ Xbf,
                                             unsigned short* __restrict__ wqkvT) {
    const int b = blockIdx.x;
    const int tid = threadIdx.x;
    if (b < 4096) {
        const int i = (b * 256 + tid) * 4;
        const float4 v = *(const float4*)(X + i);
        u16x4 o;
        o[0] = f2bf(v.x); o[1] = f2bf(v.y); o[2] = f2bf(v.z); o[3] = f2bf(v.w);
        *(u16x4*)(Xbf + i) = o;
        return;
    }
    __shared__ __align__(16) unsigned short Lt[64][72];  // 9216B, 16B-aligned rows
    const int b2 = b - 4096;                 // 0..1535
    const int kb = (b2 & 31) * 64;           // k-dim base (rows of W), 32 tiles
    const int nb = (b2 >> 5) * 64;           // fused out-col base 0..3071, 48 tiles
    const float* src; int scol, sld;
    if (nb < 2048)      { src = Wq; scol = nb;        sld = 2048; }
    else if (nb < 2560) { src = Wk; scol = nb - 2048; sld = 512;  }
    else                { src = Wv; scol = nb - 2560; sld = 512;  }
    const int r16 = tid >> 4, c4 = tid & 15;
#pragma unroll
    for (int i = 0; i < 4; i++) {
        const int row = r16 + 16 * i;
        const float4 v = *(const float4*)(src + (size_t)(kb + row) * sld + scol + c4 * 4);
        u16x4 o;
        o[0] = f2bf(v.x); o[1] = f2bf(v.y); o[2] = f2bf(v.z); o[3] = f2bf(v.w);
        *(u16x4*)&Lt[row][c4 * 4] = o;
    }
    __syncthreads();
#pragma unroll
    for (int i = 0; i < 4; i++) {
        const int orow = r16 + 16 * i;       // n-dim within tile
        u16x4 o;
#pragma unroll
        for (int j = 0; j < 4; j++) o[j] = Lt[c4 * 4 + j][orow];
        *(u16x4*)&wqkvT[(size_t)(nb + orow) * 2048 + kb + c4 * 4] = o;
    }
}

// ---------------------------------------------------------------------------
// prep2: Wo f32->bf16 transpose -> woT ONLY (1024 blocks, 64x64 float4
// tiles). V^T is now produced directly by gemm128_qkv's epilogue.
// ---------------------------------------------------------------------------
__global__ __launch_bounds__(256) void prep2(const float* __restrict__ Wo,
                                             unsigned short* __restrict__ woT) {
    const int b = blockIdx.x;
    const int tid = threadIdx.x;
    __shared__ __align__(16) unsigned short Lt[64][72];
    const int r16 = tid >> 4, c4 = tid & 15;
    const int kb = (b & 31) * 64;
    const int nb = (b >> 5) * 64;
#pragma unroll
    for (int i = 0; i < 4; i++) {
        const int row = r16 + 16 * i;
        const float4 v = *(const float4*)(Wo + (size_t)(kb + row) * 2048 + nb + c4 * 4);
        u16x4 o;
        o[0] = f2bf(v.x); o[1] = f2bf(v.y); o[2] = f2bf(v.z); o[3] = f2bf(v.w);
        *(u16x4*)&Lt[row][c4 * 4] = o;
    }
    __syncthreads();
#pragma unroll
    for (int i = 0; i < 4; i++) {
        const int orow = r16 + 16 * i;
        u16x4 o;
#pragma unroll
        for (int j = 0; j < 4; j++) o[j] = Lt[c4 * 4 + j][orow];
        *(u16x4*)&woT[(size_t)(nb + orow) * 2048 + kb + c4 * 4] = o;
    }
}

// ---------------------------------------------------------------------------
// gemm128_qkv: QKV = Xbf @ wqkvT^T, m97-exact 128x128 tile BK=64, 4 waves
// 2x2 (64x64/wave), glds16 staging, RoPE fused, bf16 out ldc=3072.
// NEW: blocks with bn >= 2560 (the V columns) write their accumulators
// TRANSPOSED straight into vt[512][2048] (u16x4 = 4 consecutive s-rows per
// lane) instead of into qkv -- prep2's V transpose pass is eliminated.
// vt lives in d_out's free tail, so no overlap with live Xbf/wqkvT.
// ---------------------------------------------------------------------------
__global__ __launch_bounds__(256) void gemm128_qkv(const unsigned short* __restrict__ A,
                                                   const unsigned short* __restrict__ BT,
                                                   unsigned short* __restrict__ C,
                                                   unsigned short* __restrict__ vt) {
    __shared__ __align__(16) unsigned short As[128 * 64];
    __shared__ __align__(16) unsigned short Bs[128 * 64];

    const int tid = threadIdx.x;
    const int lane = tid & 63;
    const int wave = tid >> 6;
    const int quad = lane >> 4;
    const int l15 = lane & 15;
    const int bm = blockIdx.x * 128;
    const int bn = blockIdx.y * 128;
    const int wm = (wave & 1) * 64;
    const int wn = (wave >> 1) * 64;

    const int srow = wave * 8 + (lane >> 3);      // 0..31 (+32 per call)
    const int sw8 = (lane & 7) ^ (srow & 7);
    const unsigned short* Ag = A + (size_t)(bm + srow) * 2048 + sw8 * 8;
    const unsigned short* Bg = BT + (size_t)(bn + srow) * 2048 + sw8 * 8;
    unsigned short* Asl = As + wave * 512;        // + i*2048 per call
    unsigned short* Bsl = Bs + wave * 512;

    f32x4 acc[4][4] = {};

    for (int k0 = 0; k0 < 2048; k0 += 64) {
#pragma unroll
        for (int i = 0; i < 4; i++) {
            glds16(Ag + (size_t)(32 * i) * 2048 + k0, Asl + i * 2048);
            glds16(Bg + (size_t)(32 * i) * 2048 + k0, Bsl + i * 2048);
        }
        __syncthreads();
#pragma unroll
        for (int ks = 0; ks < 2; ks++) {
            bf16x8 af[4], bfr[4];
#pragma unroll
            for (int mt = 0; mt < 4; mt++) {
                const int row = wm + 16 * mt + l15;
                af[mt] = __builtin_bit_cast(bf16x8,
                    *(const u32x4*)&As[row * 64 + (((quad + 4 * ks) ^ (row & 7)) * 8)]);
            }
#pragma unroll
            for (int nt = 0; nt < 4; nt++) {
                const int row = wn + 16 * nt + l15;
                bfr[nt] = __builtin_bit_cast(bf16x8,
                    *(const u32x4*)&Bs[row * 64 + (((quad + 4 * ks) ^ (row & 7)) * 8)]);
            }
#pragma unroll
            for (int mt = 0; mt < 4; mt++)
#pragma unroll
                for (int nt = 0; nt < 4; nt++)
                    acc[mt][nt] = MFMA16(af[mt], bfr[nt], acc[mt][nt]);
        }
        __syncthreads();
    }

    if (bn >= 2560) {
        // V columns: write V^T directly (no RoPE). vt[d][s], d=col-2560.
#pragma unroll
        for (int mt = 0; mt < 4; mt++)
#pragma unroll
            for (int nt = 0; nt < 4; nt++) {
                const int d = bn + wn + 16 * nt + l15 - 2560;
                const int row0 = bm + wm + 16 * mt + quad * 4;
                u16x4 o;
#pragma unroll
                for (int r = 0; r < 4; r++) o[r] = f2bf(acc[mt][nt][r]);
                *(u16x4*)&vt[(size_t)d * 2048 + row0] = o;
            }
        return;
    }

    // Q|K columns: fused RoPE (pairwise via shfl), bf16 store into qkv
#pragma unroll
    for (int mt = 0; mt < 4; mt++) {
#pragma unroll
        for (int nt = 0; nt < 4; nt++) {
            const int col = bn + wn + 16 * nt + l15;
            const int i = (col & 63) >> 1;
            const float inv = exp2f(-0.41524101186092036f * (float)i);
            const float sign = (col & 1) ? 1.0f : -1.0f;
#pragma unroll
            for (int r = 0; r < 4; r++) {
                const int row = bm + wm + 16 * mt + quad * 4 + r;
                float sn, cs;
                __sincosf((float)row * inv, &sn, &cs);
                const float partner = __shfl_xor(acc[mt][nt][r], 1, 64);
                acc[mt][nt][r] = acc[mt][nt][r] * cs + sign * partner * sn;
            }
#pragma unroll
            for (int r = 0; r < 4; r++) {
                const int row = bm + wm + 16 * mt + quad * 4 + r;
                C[(size_t)row * 3072 + col] = f2bf(acc[mt][nt][r]);
            }
        }
    }
}

// ---------------------------------------------------------------------------
// GEMM: C[M][N] = A[M][K] @ BT[N][K]^T (bf16 in, fp32 accum), m97 structure,
// BK=128; used for out-proj (BM=64: 512 blocks = 2/CU).
// ---------------------------------------------------------------------------
template <int BM>
__global__ __launch_bounds__(256) void gemm_bt(const unsigned short* __restrict__ A,
                                               const unsigned short* __restrict__ BT,
                                               void* __restrict__ Cv,
                                               int K, int lda, int ldb, int ldc,
                                               int out_f32) {
    constexpr int MT = BM / 32;
    constexpr int ACALLS = BM / 16;   // 4KB-chunks for A tile
    __shared__ __align__(16) unsigned short As[BM * 128];
    __shared__ __align__(16) unsigned short Bs[128 * 128];

    const int tid = threadIdx.x;
    const int lane = tid & 63;
    const int wave = tid >> 6;
    const int quad = lane >> 4;
    const int l15 = lane & 15;
    const int bm = blockIdx.x * BM;
    const int bn = blockIdx.y * 128;
    const int wm = (wave & 1) * (BM / 2);
    const int wn = (wave >> 1) * 64;

    // staging: call i covers rows 16i..16i+16; lane row-in-call = wave*4 + (lane>>4)
    const int srow = wave * 4 + (lane >> 4);          // 0..15
    const int sw = (lane & 15) ^ (srow & 7);          // swizzled chunk 0..15
    const unsigned short* Ag = A + (size_t)(bm + srow) * lda + sw * 8;
    const unsigned short* Bg = BT + (size_t)(bn + srow) * ldb + sw * 8;
    unsigned short* Asl = As + wave * 512;            // + i*2048 per call
    unsigned short* Bsl = Bs + wave * 512;

    f32x4 acc[MT][4] = {};

    for (int k0 = 0; k0 < K; k0 += 128) {
#pragma unroll
        for (int i = 0; i < ACALLS; i++)
            glds16(Ag + (size_t)(16 * i) * lda + k0, Asl + i * 2048);
#pragma unroll
        for (int i = 0; i < 8; i++)
            glds16(Bg + (size_t)(16 * i) * ldb + k0, Bsl + i * 2048);
        __syncthreads();
#pragma unroll
        for (int ks = 0; ks < 4; ks++) {
            bf16x8 af[MT], bfr[4];
#pragma unroll
            for (int mt = 0; mt < MT; mt++) {
                const int row = wm + 16 * mt + l15;
                af[mt] = __builtin_bit_cast(bf16x8,
                    *(const u32x4*)&As[row * 128 + (((quad + 4 * ks) ^ (row & 7)) * 8)]);
            }
#pragma unroll
            for (int nt = 0; nt < 4; nt++) {
                const int row = wn + 16 * nt + l15;
                bfr[nt] = __builtin_bit_cast(bf16x8,
                    *(const u32x4*)&Bs[row * 128 + (((quad + 4 * ks) ^ (row & 7)) * 8)]);
            }
#pragma unroll
            for (int mt = 0; mt < MT; mt++)
#pragma unroll
                for (int nt = 0; nt < 4; nt++)
                    acc[mt][nt] = MFMA16(af[mt], bfr[nt], acc[mt][nt]);
        }
        __syncthreads();
    }

    // epilogue: C/D layout col = l15, row = quad*4 + r
#pragma unroll
    for (int mt = 0; mt < MT; mt++) {
#pragma unroll
        for (int nt = 0; nt < 4; nt++) {
#pragma unroll
            for (int r = 0; r < 4; r++) {
                const int row = bm + wm + 16 * mt + quad * 4 + r;
                const int col = bn + wn + 16 * nt + l15;
                if (out_f32)
                    ((float*)Cv)[(size_t)row * ldc + col] = acc[mt][nt][r];
                else
                    ((unsigned short*)Cv)[(size_t)row * ldc + col] = f2bf(acc[mt][nt][r]);
            }
        }
    }
}

// ---------------------------------------------------------------------------
// Flash attention -- round-0 best-measured structure + QSCALE fold +
// setprio (69us config, frozen). NEW: 1D 512-block grid with XCD-clustered
// decode: kvh = bid & 7, so (with the round-robin bid%8 -> XCD mapping)
// XCD i only ever touches kv-head i's 512KB of K/V, which stays resident
// in that XCD's 4MB L2 across all 16 K-iterations -> the serial staging
// drain waits on local-L2 (~200cy) instead of HBM/remote (~900cy).
// qkv: [2048][3072] bf16 (Q|K|V, RoPE applied); vt: [512][2048] = V^T.
// ---------------------------------------------------------------------------
__global__ __launch_bounds__(256) void attn_kernel(const unsigned short* __restrict__ qkv,
                                                   const unsigned short* __restrict__ vt,
                                                   unsigned short* __restrict__ attn_out) {
    const int bid = blockIdx.x;
    const int kvh = bid & 7;            // XCD-clustered kv-head
    const int sub = bid >> 3;           // 0..63
    const int h = kvh * 4 + (sub & 3);  // head within kv group
    const int qb = sub >> 2;            // 0..15
    const int tid = threadIdx.x;
    const int lane = tid & 63;
    const int wave = tid >> 6;
    const int quad = lane >> 4;
    const int l15 = lane & 15;
    const int w0 = qb * 128 + wave * 32;

    __shared__ __align__(16) unsigned short Ks[128 * 64];   // K rows x 64 d
    __shared__ __align__(16) unsigned short Vs[64 * 128];   // V^T: 64 d x 128 kv
    __shared__ __align__(16) unsigned short St[4][32][72];  // per-wave P (q x kv)
    unsigned short (*Sw)[72] = St[wave];

    // K staging map (64-u16 rows, 8 chunk slots)
    const int srow = wave * 8 + (lane >> 3);
    const int swK = (lane & 7) ^ (srow & 7);
    const unsigned short* Kg = qkv + 2048 + kvh * 64 + swK * 8;  // + (kbase+srow+32i)*3072
    unsigned short* Ksl = Ks + wave * 512;
    // V staging map (128-u16 rows, 16 chunk slots)
    const int vrow = wave * 4 + (lane >> 4);
    const int swV = (lane & 15) ^ (vrow & 7);
    const unsigned short* Vg = vt + (size_t)(kvh * 64 + vrow) * 2048 + swV * 8;  // + 16i*2048 + kbase
    unsigned short* Vsl = Vs + wave * 512;

    // Q fragments (MFMA B-operand: n=q=l15, k=quad*8+j), pre-scaled by
    // log2e/8 (shift-invariant softmax: no exponent bias needed).
    const float QSCALE = 0.18033688011111093f;  // 0.125 * log2(e)
    bf16x8 qf[2][2];
#pragma unroll
    for (int mt = 0; mt < 2; mt++)
#pragma unroll
        for (int ks = 0; ks < 2; ks++) {
            u32x4 raw = *(const u32x4*)&qkv[(size_t)(w0 + 16 * mt + l15) * 3072 + h * 64 + quad * 8 + 32 * ks];
            u16x8 t = __builtin_bit_cast(u16x8, raw);
#pragma unroll
            for (int j = 0; j < 8; j++) t[j] = f2bf(bf2f(t[j]) * QSCALE);
            qf[mt][ks] = __builtin_bit_cast(bf16x8, t);
        }

    bf16x8 ones;
#pragma unroll
    for (int j = 0; j < 8; j++) ones[j] = (__bf16)1.0f;

    f32x4 acc_o[2][4] = {};
    f32x4 acc_l[2] = {};

    for (int kb2 = 0; kb2 < 16; kb2++) {
        const int kbase = kb2 * 128;
#pragma unroll
        for (int i = 0; i < 4; i++) {
            glds16(Kg + (size_t)(kbase + srow + 32 * i) * 3072, Ksl + i * 2048);
            glds16(Vg + (size_t)(16 * i) * 2048 + kbase, Vsl + i * 2048);
        }
        __syncthreads();

#pragma unroll
        for (int kh = 0; kh < 2; kh++) {
            // S^T = K Q^T : A = K-frag (m=kv), B = Q-frag (n=q)
            f32x4 st[2][4] = {};
            __builtin_amdgcn_s_setprio(1);
#pragma unroll
            for (int n = 0; n < 4; n++) {
                const int row = kh * 64 + 16 * n + l15;
                const bf16x8 kf0 = __builtin_bit_cast(bf16x8,
                    *(const u32x4*)&Ks[row * 64 + ((quad ^ (l15 & 7)) * 8)]);
                const bf16x8 kf1 = __builtin_bit_cast(bf16x8,
                    *(const u32x4*)&Ks[row * 64 + (((quad + 4) ^ (l15 & 7)) * 8)]);
#pragma unroll
                for (int mt = 0; mt < 2; mt++) {
                    st[mt][n] = MFMA16(kf0, qf[mt][0], st[mt][n]);
                    st[mt][n] = MFMA16(kf1, qf[mt][1], st[mt][n]);
                }
            }
            __builtin_amdgcn_s_setprio(0);

            // p = exp2(st); lane holds q=l15, kv=16n+quad*4+r
            // -> contiguous b64 store into Sw[q][kv]
#pragma unroll
            for (int mt = 0; mt < 2; mt++)
#pragma unroll
                for (int n = 0; n < 4; n++) {
                    u16x4 pk;
#pragma unroll
                    for (int r = 0; r < 4; r++)
                        pk[r] = f2bf(exp2f(st[mt][n][r]));
                    *(u16x4*)&Sw[16 * mt + l15][16 * n + quad * 4] = pk;
                }

            // P A-frags (m=q=l15, k=kv=quad*8+j) straight from Sw rows
            bf16x8 pf[2][2];
#pragma unroll
            for (int mt = 0; mt < 2; mt++) {
                pf[mt][0] = __builtin_bit_cast(bf16x8, *(const u32x4*)&Sw[16 * mt + l15][quad * 8]);
                pf[mt][1] = __builtin_bit_cast(bf16x8, *(const u32x4*)&Sw[16 * mt + l15][quad * 8 + 32]);
            }

            __builtin_amdgcn_s_setprio(1);
            // row sums: acc_l[mt] += P @ ones  (C-rows match acc_o's rows)
#pragma unroll
            for (int mt = 0; mt < 2; mt++) {
                acc_l[mt] = MFMA16(pf[mt][0], ones, acc_l[mt]);
                acc_l[mt] = MFMA16(pf[mt][1], ones, acc_l[mt]);
            }

            // O += P @ V : B = V^T rows (n=d=l15, k=kv)
#pragma unroll
            for (int nt = 0; nt < 4; nt++) {
                const int row = 16 * nt + l15;
                const int c0 = kh * 8 + (quad ^ (l15 & 7));
                const int c1 = kh * 8 + ((quad + 4) ^ (l15 & 7));
                const bf16x8 vf0 = __builtin_bit_cast(bf16x8, *(const u32x4*)&Vs[row * 128 + c0 * 8]);
                const bf16x8 vf1 = __builtin_bit_cast(bf16x8, *(const u32x4*)&Vs[row * 128 + c1 * 8]);
#pragma unroll
                for (int mt = 0; mt < 2; mt++) {
                    acc_o[mt][nt] = MFMA16(pf[mt][0], vf0, acc_o[mt][nt]);
                    acc_o[mt][nt] = MFMA16(pf[mt][1], vf1, acc_o[mt][nt]);
                }
            }
            __builtin_amdgcn_s_setprio(0);
        }
        __syncthreads();
    }

    // epilogue: acc_o and acc_l share lane layout q=quad*4+r (+16mt), d=16nt+l15
#pragma unroll
    for (int mt = 0; mt < 2; mt++) {
        float linv[4];
#pragma unroll
        for (int r = 0; r < 4; r++) linv[r] = 1.0f / acc_l[mt][r];
#pragma unroll
        for (int nt = 0; nt < 4; nt++)
#pragma unroll
            for (int r = 0; r < 4; r++)
                attn_out[(size_t)(w0 + 16 * mt + quad * 4 + r) * 2048 + h * 64 + 16 * nt + l15] =
                    f2bf(acc_o[mt][nt][r] * linv[r]);
    }
}

// ---------------------------------------------------------------------------
extern "C" void kernel_launch(void* const* d_in, const int* in_sizes, int n_in,
                              void* d_out, int out_size, void* d_ws, size_t ws_size,
                              hipStream_t stream) {
    (void)in_sizes; (void)n_in; (void)out_size; (void)ws_size;

    const float* X  = (const float*)d_in[0];
    const float* Wq = (const float*)d_in[1];
    const float* Wk = (const float*)d_in[2];
    const float* Wv = (const float*)d_in[3];
    const float* Wo = (const float*)d_in[4];

    // ws (u16): phase1 Xbf[0..4.19M) wqkvT[4.19M..10.49M)
    //           phase2 attnO[1.05M..5.24M) woT[5.24M..9.44M)
    // d_out (u16): qkv Q|K cols [0..6.29M); vt parks in free tail
    //   [6.29M..7.34M) (written by gemm128_qkv epilogue, read by attn,
    //   dead before the final f32 GEMM overwrites all of d_out).
    unsigned short* ws16  = (unsigned short*)d_ws;
    unsigned short* Xbf   = ws16;
    unsigned short* wqkvT = ws16 + (size_t)4194304;
    unsigned short* qkv   = (unsigned short*)d_out;
    unsigned short* vt    = (unsigned short*)d_out + (size_t)6291456;
    unsigned short* attnO = ws16 + (size_t)1048576;
    unsigned short* woT   = ws16 + (size_t)5242880;

    // X cvt (4096 blocks) + Wqkv 64x64 float4 transpose (1536 blocks)
    prep1<<<5632, 256, 0, stream>>>(X, Wq, Wk, Wv, Xbf, wqkvT);

    // QKV = X @ [Wq|Wk|Wv] -> Q|K (RoPE'd) into qkv, V^T straight into vt
    gemm128_qkv<<<dim3(16, 24), 256, 0, stream>>>(Xbf, wqkvT, qkv, vt);

    // Wo 64x64 float4 transpose (1024 blocks, into dead wqkvT region)
    prep2<<<1024, 256, 0, stream>>>(Wo, woT);

    // attention -> attnO (bf16); 1D grid, XCD-clustered kv-heads
    attn_kernel<<<512, 256, 0, stream>>>(qkv, vt, attnO);

    // out = attnO @ Wo -> f32 into d_out (overwrites dead qkv+vt)
    gemm_bt<64><<<dim3(32, 16), 256, 0, stream>>>(attnO, woT, (void*)d_out, 2048, 2048, 2048, 2048, 1);
}